// Round 1
// baseline (404.348 us; speedup 1.0000x reference)
//
#include <hip/hip_runtime.h>
#include <math.h>

#define NUSER 2560
#define NITEM 3584
#define NN    6144
#define EDIM  64
#define NNZ   200000
#define DQK   256
#define KTOP  5
#define SPLITS 8
#define CTILES 48        // 6144 / 128 candidate tiles
#define TPB   256

// ---------------------------------------------------------------- utility
__global__ void zero_kernel(float4* __restrict__ p, int n4) {
    int i = blockIdx.x * TPB + threadIdx.x;
    if (i < n4) p[i] = make_float4(0.f, 0.f, 0.f, 0.f);
}

// ---------------------------------------------------------------- SpMM (COO, atomic scatter)
// dst[r*64+e] += scale * v * src[c*64+e]; one thread per (nnz, e); lanes cover e -> coalesced.
__global__ void spmm_emb_kernel(const int* __restrict__ rows, const int* __restrict__ cols,
                                const float* __restrict__ vals,
                                const float* __restrict__ user, const float* __restrict__ item,
                                float* __restrict__ dst) {
    int gid = blockIdx.x * TPB + threadIdx.x;   // exactly NNZ*64 threads
    int nz = gid >> 6, e = gid & 63;
    int r = rows[nz], c = cols[nz];
    float v = vals[nz];
    float x = (c < NUSER) ? user[c * EDIM + e] : item[(c - NUSER) * EDIM + e];
    atomicAdd(&dst[r * EDIM + e], v * x);
}

__global__ void spmm_kernel(const int* __restrict__ rows, const int* __restrict__ cols,
                            const float* __restrict__ vals,
                            const float* __restrict__ src, float* __restrict__ dst, float scale) {
    int gid = blockIdx.x * TPB + threadIdx.x;
    int nz = gid >> 6, e = gid & 63;
    int r = rows[nz], c = cols[nz];
    float v = vals[nz] * scale;
    atomicAdd(&dst[r * EDIM + e], v * src[c * EDIM + e]);
}

// ---------------------------------------------------------------- Qm = ego2 copy ; out_mean = (ego0+ego1)/2
__global__ void copy_mean_kernel(const float4* __restrict__ ego2, const float4* __restrict__ ego1,
                                 const float4* __restrict__ user, const float4* __restrict__ item,
                                 float4* __restrict__ Qm, float4* __restrict__ outmean) {
    int i = blockIdx.x * TPB + threadIdx.x;      // < NN*EDIM/4 = 98304
    float4 e2 = ego2[i];
    Qm[i] = e2;
    int row = i >> 4;                            // 16 float4 per row
    float4 e0 = (row < NUSER) ? user[i] : item[i - NUSER * (EDIM / 4)];
    float4 e1 = ego1[i];
    float4 m;
    m.x = 0.5f * (e0.x + e1.x); m.y = 0.5f * (e0.y + e1.y);
    m.z = 0.5f * (e0.z + e1.z); m.w = 0.5f * (e0.w + e1.w);
    outmean[i] = m;
}

// ---------------------------------------------------------------- QKV GEMM: out[r][d] = ego2[r]·W[d] + b[d]
// grid (96 rowtiles, 2 dtiles(128), 3 matrices); block 256; 64x128 out tile; 4x8 microtile, K=64
__global__ __launch_bounds__(TPB, 3) void qkv_gemm_kernel(
        const float* __restrict__ A,
        const float* __restrict__ Wq, const float* __restrict__ bq,
        const float* __restrict__ Wk, const float* __restrict__ bk,
        const float* __restrict__ Wv, const float* __restrict__ bv,
        float* __restrict__ Qa, float* __restrict__ Ka, float* __restrict__ Va) {
    const float* W; const float* b; float* out;
    if (blockIdx.z == 0)      { W = Wq; b = bq; out = Qa; }
    else if (blockIdx.z == 1) { W = Wk; b = bk; out = Ka; }
    else                      { W = Wv; b = bv; out = Va; }

    __shared__ __align__(16) float smem[64 * 64 + 128 * 64];
    float* As = smem;            // [e][r] stride 64
    float* Bs = smem + 4096;     // [e][d] stride 128
    int t = threadIdx.x, tx = t & 15, ty = t >> 4;
    int r0 = blockIdx.x * 64, d0 = blockIdx.y * 128;

    { // A tile transposed
        int r = t & 63, eb = (t >> 6) * 16;
#pragma unroll
        for (int rep = 0; rep < 4; ++rep) {
            int e0 = eb + rep * 4;
            float4 v = *(const float4*)&A[(r0 + r) * EDIM + e0];
            As[(e0 + 0) * 64 + r] = v.x; As[(e0 + 1) * 64 + r] = v.y;
            As[(e0 + 2) * 64 + r] = v.z; As[(e0 + 3) * 64 + r] = v.w;
        }
    }
    { // B tile transposed
        int d = t & 127, eb = (t >> 7) * 32;
#pragma unroll
        for (int rep = 0; rep < 8; ++rep) {
            int e0 = eb + rep * 4;
            float4 v = *(const float4*)&W[(d0 + d) * EDIM + e0];
            Bs[(e0 + 0) * 128 + d] = v.x; Bs[(e0 + 1) * 128 + d] = v.y;
            Bs[(e0 + 2) * 128 + d] = v.z; Bs[(e0 + 3) * 128 + d] = v.w;
        }
    }
    __syncthreads();

    float acc[4][8];
#pragma unroll
    for (int i = 0; i < 4; ++i)
#pragma unroll
        for (int j = 0; j < 8; ++j) acc[i][j] = 0.f;

#pragma unroll 4
    for (int e = 0; e < 64; ++e) {
        float4 a  = *(const float4*)&As[e * 64 + ty * 4];
        float4 b0 = *(const float4*)&Bs[e * 128 + tx * 4];
        float4 b1 = *(const float4*)&Bs[e * 128 + 64 + tx * 4];
        float ar[4] = {a.x, a.y, a.z, a.w};
#pragma unroll
        for (int i = 0; i < 4; ++i) {
            acc[i][0] = fmaf(ar[i], b0.x, acc[i][0]);
            acc[i][1] = fmaf(ar[i], b0.y, acc[i][1]);
            acc[i][2] = fmaf(ar[i], b0.z, acc[i][2]);
            acc[i][3] = fmaf(ar[i], b0.w, acc[i][3]);
            acc[i][4] = fmaf(ar[i], b1.x, acc[i][4]);
            acc[i][5] = fmaf(ar[i], b1.y, acc[i][5]);
            acc[i][6] = fmaf(ar[i], b1.z, acc[i][6]);
            acc[i][7] = fmaf(ar[i], b1.w, acc[i][7]);
        }
    }
    float4 bias0 = *(const float4*)&b[d0 + tx * 4];
    float4 bias1 = *(const float4*)&b[d0 + 64 + tx * 4];
#pragma unroll
    for (int i = 0; i < 4; ++i) {
        int r = r0 + ty * 4 + i;
        float4 o0 = make_float4(acc[i][0] + bias0.x, acc[i][1] + bias0.y,
                                acc[i][2] + bias0.z, acc[i][3] + bias0.w);
        float4 o1 = make_float4(acc[i][4] + bias1.x, acc[i][5] + bias1.y,
                                acc[i][6] + bias1.z, acc[i][7] + bias1.w);
        *(float4*)&out[r * DQK + d0 + tx * 4] = o0;
        *(float4*)&out[r * DQK + d0 + 64 + tx * 4] = o1;
    }
}

// ---------------------------------------------------------------- fused sim top-5 (partial over cand split)
// sim2[r][c] = Qm[r]·P[c]; per block: 64 rows x (CTILES/SPLITS) tiles of 128 cands.
__global__ __launch_bounds__(TPB, 3) void topk_partial_kernel(
        const float* __restrict__ Qm, const float* __restrict__ P,
        float* __restrict__ pval, int* __restrict__ pidx) {
    __shared__ __align__(16) float smem[64 * 64 + 128 * 64];
    float* Qs = smem;            // [e][r] stride 64
    float* Ps = smem + 4096;     // [e][c] stride 128
    int t = threadIdx.x, tx = t & 15, ty = t >> 4;
    int r0 = blockIdx.x * 64;
    int s  = blockIdx.y;
    const int ntiles = CTILES / SPLITS;

    { // Q tile transposed (once)
        int r = t & 63, eb = (t >> 6) * 16;
#pragma unroll
        for (int rep = 0; rep < 4; ++rep) {
            int e0 = eb + rep * 4;
            float4 v = *(const float4*)&Qm[(r0 + r) * EDIM + e0];
            Qs[(e0 + 0) * 64 + r] = v.x; Qs[(e0 + 1) * 64 + r] = v.y;
            Qs[(e0 + 2) * 64 + r] = v.z; Qs[(e0 + 3) * 64 + r] = v.w;
        }
    }

    float t5v[4][5]; int t5i[4][5];
#pragma unroll
    for (int i = 0; i < 4; ++i)
#pragma unroll
        for (int k = 0; k < 5; ++k) { t5v[i][k] = -INFINITY; t5i[i][k] = 0x7fffffff; }

    for (int tile = 0; tile < ntiles; ++tile) {
        int c0 = (s * ntiles + tile) * 128;
        __syncthreads();          // previous compute done (and Q-load on first iter)
        { // P tile transposed
            int c = t & 127, eb = (t >> 7) * 32;
#pragma unroll
            for (int rep = 0; rep < 8; ++rep) {
                int e0 = eb + rep * 4;
                float4 v = *(const float4*)&P[(c0 + c) * EDIM + e0];
                Ps[(e0 + 0) * 128 + c] = v.x; Ps[(e0 + 1) * 128 + c] = v.y;
                Ps[(e0 + 2) * 128 + c] = v.z; Ps[(e0 + 3) * 128 + c] = v.w;
            }
        }
        __syncthreads();

        float acc[4][8];
#pragma unroll
        for (int i = 0; i < 4; ++i)
#pragma unroll
            for (int j = 0; j < 8; ++j) acc[i][j] = 0.f;

#pragma unroll 4
        for (int e = 0; e < 64; ++e) {
            float4 a  = *(const float4*)&Qs[e * 64 + ty * 4];
            float4 b0 = *(const float4*)&Ps[e * 128 + tx * 4];
            float4 b1 = *(const float4*)&Ps[e * 128 + 64 + tx * 4];
            float ar[4] = {a.x, a.y, a.z, a.w};
#pragma unroll
            for (int i = 0; i < 4; ++i) {
                acc[i][0] = fmaf(ar[i], b0.x, acc[i][0]);
                acc[i][1] = fmaf(ar[i], b0.y, acc[i][1]);
                acc[i][2] = fmaf(ar[i], b0.z, acc[i][2]);
                acc[i][3] = fmaf(ar[i], b0.w, acc[i][3]);
                acc[i][4] = fmaf(ar[i], b1.x, acc[i][4]);
                acc[i][5] = fmaf(ar[i], b1.y, acc[i][5]);
                acc[i][6] = fmaf(ar[i], b1.z, acc[i][6]);
                acc[i][7] = fmaf(ar[i], b1.w, acc[i][7]);
            }
        }
        // top-5 update (strict > keeps the earlier/lower index on ties; per-thread cand order is increasing)
#pragma unroll
        for (int i = 0; i < 4; ++i) {
#pragma unroll
            for (int j = 0; j < 8; ++j) {
                float v = acc[i][j];
                if (v > t5v[i][4]) {
                    int ci = c0 + ((j < 4) ? (tx * 4 + j) : (64 + tx * 4 + (j - 4)));
#pragma unroll
                    for (int k = 4; k >= 1; --k) {
                        bool sh = v > t5v[i][k];
                        bool ph = v > t5v[i][k - 1];
                        float nv = ph ? t5v[i][k - 1] : v;
                        int   ni = ph ? t5i[i][k - 1] : ci;
                        if (sh) { t5v[i][k] = nv; t5i[i][k] = ni; }
                    }
                    if (v > t5v[i][0]) { t5v[i][0] = v; t5i[i][0] = ci; }
                }
            }
        }
    }

    // merge 16 per-thread lists per row (stride 81 padding kills bank conflicts)
    __syncthreads();
    float* mv = smem;                       // 64*81 floats
    int*   mi = (int*)(smem + 64 * 81);     // 64*81 ints
#pragma unroll
    for (int i = 0; i < 4; ++i) {
        int rowl = ty * 4 + i;
#pragma unroll
        for (int k = 0; k < 5; ++k) {
            mv[rowl * 81 + tx * 5 + k] = t5v[i][k];
            mi[rowl * 81 + tx * 5 + k] = t5i[i][k];
        }
    }
    __syncthreads();
    if (t < 64) {
        int rowl = t;
        float pvL = INFINITY; int piL = -1;
        for (int k = 0; k < KTOP; ++k) {
            float bv = -INFINITY; int bi = 0x7fffffff;
            for (int n = 0; n < 80; ++n) {
                float v = mv[rowl * 81 + n];
                int   x = mi[rowl * 81 + n];
                bool worse_prev  = (v < pvL) || (v == pvL && x > piL);
                bool better_best = (v > bv)  || (v == bv  && x < bi);
                if (worse_prev && better_best) { bv = v; bi = x; }
            }
            int o = ((r0 + rowl) * SPLITS + s) * KTOP + k;
            pval[o] = bv; pidx[o] = bi;
            pvL = bv; piL = bi;
        }
    }
}

// ---------------------------------------------------------------- final merge across splits
__global__ void topk_final_kernel(const float* __restrict__ pval, const int* __restrict__ pidx,
                                  int* __restrict__ idxout) {
    int r = blockIdx.x * TPB + threadIdx.x;   // exactly NN threads
    const float* pv = pval + r * SPLITS * KTOP;
    const int*   pi = pidx + r * SPLITS * KTOP;
    float prevv = INFINITY; int previ = -1;
    for (int k = 0; k < KTOP; ++k) {
        float bv = -INFINITY; int bi = 0x7fffffff;
        for (int n = 0; n < SPLITS * KTOP; ++n) {
            float v = pv[n]; int x = pi[n];
            bool worse_prev  = (v < prevv) || (v == prevv && x > previ);
            bool better_best = (v > bv)    || (v == bv    && x < bi);
            if (worse_prev && better_best) { bv = v; bi = x; }
        }
        idxout[r * KTOP + k] = bi;
        prevv = bv; previ = bi;
    }
}

// ---------------------------------------------------------------- attention epilogue (one wave per row)
__global__ __launch_bounds__(TPB) void attn_kernel(
        const float* __restrict__ Qa, const float* __restrict__ Ka, const float* __restrict__ Va,
        const int* __restrict__ idx, float* __restrict__ out) {
    int wv = threadIdx.x >> 6, lane = threadIdx.x & 63;
    int r = blockIdx.x * 4 + wv;
    int cI[KTOP];
#pragma unroll
    for (int k = 0; k < KTOP; ++k) cI[k] = idx[r * KTOP + k];
    float4 q = *(const float4*)&Qa[r * DQK + lane * 4];
    float sc[KTOP];
#pragma unroll
    for (int k = 0; k < KTOP; ++k) {
        float4 kk = *(const float4*)&Ka[cI[k] * DQK + lane * 4];
        float p = q.x * kk.x + q.y * kk.y + q.z * kk.z + q.w * kk.w;
#pragma unroll
        for (int off = 32; off; off >>= 1) p += __shfl_xor(p, off, 64);
        sc[k] = p * 0.0625f;   // 1/sqrt(256)
    }
    float m = sc[0];
#pragma unroll
    for (int k = 1; k < KTOP; ++k) m = fmaxf(m, sc[k]);
    float w[KTOP], ssum = 0.f;
#pragma unroll
    for (int k = 0; k < KTOP; ++k) { w[k] = expf(sc[k] - m); ssum += w[k]; }
    float inv = 1.f / ssum;
    float4 o = make_float4(0.f, 0.f, 0.f, 0.f);
#pragma unroll
    for (int k = 0; k < KTOP; ++k) {
        float4 vv = *(const float4*)&Va[cI[k] * DQK + lane * 4];
        float a = w[k] * inv;
        o.x = fmaf(a, vv.x, o.x); o.y = fmaf(a, vv.y, o.y);
        o.z = fmaf(a, vv.z, o.z); o.w = fmaf(a, vv.w, o.w);
    }
    *(float4*)&out[r * DQK + lane * 4] = o;
}

// ---------------------------------------------------------------- launch
extern "C" void kernel_launch(void* const* d_in, const int* in_sizes, int n_in,
                              void* d_out, int out_size, void* d_ws, size_t ws_size,
                              hipStream_t stream) {
    const float* user  = (const float*)d_in[0];
    const float* item  = (const float*)d_in[1];
    const int*   nrows = (const int*)d_in[2];
    const int*   ncols = (const int*)d_in[3];
    const float* nvals = (const float*)d_in[4];
    const int*   arows = (const int*)d_in[5];
    const int*   acols = (const int*)d_in[6];
    const float* avals = (const float*)d_in[7];
    const float* Wq = (const float*)d_in[8];  const float* bq = (const float*)d_in[9];
    const float* Wk = (const float*)d_in[10]; const float* bk = (const float*)d_in[11];
    const float* Wv = (const float*)d_in[12]; const float* bv = (const float*)d_in[13];
    float* out = (float*)d_out;
    float* ws  = (float*)d_ws;

    const int NE = NN * EDIM;              // 393216
    float* ego1 = ws;
    float* ego2 = ws + NE;
    float* Qm   = ws + 2 * NE;
    float* Qa   = ws + 3 * NE;
    float* Ka   = Qa + NN * DQK;
    float* Va   = Ka + NN * DQK;
    float* pval = Va + NN * DQK;
    int*   pidx = (int*)(pval + NN * SPLITS * KTOP);
    int*   idxf = pidx + NN * SPLITS * KTOP;

    // 1. zero ego1+ego2 (contiguous)
    zero_kernel<<<(2 * NE / 4 + TPB - 1) / TPB, TPB, 0, stream>>>((float4*)ego1, 2 * NE / 4);
    // 2. ego1 = A_norm @ ego0  (ego0 read inline from user/item)
    spmm_emb_kernel<<<NNZ * EDIM / TPB, TPB, 0, stream>>>(nrows, ncols, nvals, user, item, ego1);
    // 3. ego2 = A_norm @ ego1
    spmm_kernel<<<NNZ * EDIM / TPB, TPB, 0, stream>>>(nrows, ncols, nvals, ego1, ego2, 1.0f);
    // 4. Qm = ego2 ; out_mean = (ego0+ego1)/2
    copy_mean_kernel<<<NE / 4 / TPB, TPB, 0, stream>>>((const float4*)ego2, (const float4*)ego1,
                                                       (const float4*)user, (const float4*)item,
                                                       (float4*)Qm, (float4*)out);
    // 5. Qm += 0.5 * A @ ego2
    spmm_kernel<<<NNZ * EDIM / TPB, TPB, 0, stream>>>(arows, acols, avals, ego2, Qm, 0.5f);
    // 6. Q_all/K_all/V_all = ego2 @ W^T + b
    qkv_gemm_kernel<<<dim3(NN / 64, DQK / 128, 3), TPB, 0, stream>>>(ego2, Wq, bq, Wk, bk, Wv, bv,
                                                                     Qa, Ka, Va);
    // 7-8. top-5 of Qm·ego2^T
    topk_partial_kernel<<<dim3(NN / 64, SPLITS), TPB, 0, stream>>>(Qm, ego2, pval, pidx);
    topk_final_kernel<<<NN / TPB, TPB, 0, stream>>>(pval, pidx, idxf);
    // 9. attention epilogue
    attn_kernel<<<NN / 4, TPB, 0, stream>>>(Qa, Ka, Va, idxf, out + NE);
}